// Round 11
// baseline (307.143 us; speedup 1.0000x reference)
//
#include <hip/hip_runtime.h>
#include <hip/hip_bf16.h>

#define Bq   32
#define Cq   64
#define NPq  192
#define NOq  72
#define PTS  (NPq * NOq)   // 13824
#define REGD 76
#define OUTD 79

typedef __attribute__((ext_vector_type(8))) short short8;
typedef __attribute__((ext_vector_type(4))) float float4v;

__device__ inline unsigned short f2bf(float x) {
    __hip_bfloat16 h = __float2bfloat16(x);
    return *reinterpret_cast<unsigned short*>(&h);
}

// ---------------------------------------------------------------------------
// Phase 0 (once): RAW transpose tables (R20). The y-blend is linear, so it
// moves into the fused pool as a C-space lerp (exact); this kernel only
// transposes [c][y][x] f32 -> [y][x][c] bf16 per (s,b,y).
// 2.4x less fundamental work than the blended build (10.9M vs 26.2M
// converts, 21.8 vs 52.5 MB writes; no 72x blend redundancy).
// Pack phase = R19's proven 2-channel cvt_pk pattern; odd LDS strides keep
// reads <=2-way. x=W pad replicates x=W-1 (same clamp trick as before).
// ---------------------------------------------------------------------------
__global__ __launch_bounds__(256) void build_raw_kernel(
    const float* __restrict__ f0,   // x2: H=10,W=25
    const float* __restrict__ f1,   // x1: H=20,W=50
    const float* __restrict__ f2,   // x0: H=40,W=100
    unsigned short* __restrict__ t0,
    unsigned short* __restrict__ t1,
    unsigned short* __restrict__ t2)
{
    __shared__ float sRow[64 * 101];

    const int tid = threadIdx.x;
    int idx = blockIdx.x;           // 0..2239  (32*10 + 32*20 + 32*40)

    const float* feat; unsigned short* tab; int H, W, SW, b, y;
    if (idx < 320)       { feat = f0; tab = t0; H = 10; W = 25;  SW = 27;
                           b = idx / 10;  y = idx - b * 10; }
    else if (idx < 960)  { idx -= 320; feat = f1; tab = t1; H = 20; W = 50;  SW = 51;
                           b = idx / 20;  y = idx - b * 20; }
    else                 { idx -= 960; feat = f2; tab = t2; H = 40; W = 100; SW = 101;
                           b = idx / 40;  y = idx - b * 40; }
    const int Wp = W + 1;

    // phase 1: read row y of all 64 channels -> LDS [c][x] f32 (coalesced)
    const int tot = 64 * W;
    for (int i = tid; i < tot; i += 256) {
        const int c = i / W;
        const int x = i - c * W;
        sRow[c * SW + x] = feat[((size_t)(b * 64 + c) * H + y) * W + x];
    }
    __syncthreads();

    // phase 2: pack transposed [x][c] bf16, 2 channels/iter (cvt_pk + dword)
    unsigned short* to = tab + ((size_t)b * H + y) * Wp * 64;
    const int tot2 = Wp * 32;
    for (int i = tid; i < tot2; i += 256) {
        const int x  = i >> 5;
        const int cp = i & 31;
        const int xx = (x < W) ? x : (W - 1);
        const float v0 = sRow[(2 * cp)     * SW + xx];
        const float v1 = sRow[(2 * cp + 1) * SW + xx];
        const __hip_bfloat162 h2 = __float22bfloat162_rn(make_float2(v0, v1));
        *(__hip_bfloat162*)(to + x * 64 + 2 * cp) = h2;
    }
}

// ---------------------------------------------------------------------------
// Fused: raw-table gather + MFMA with C-SPACE x-lerp AND y-lerp + gate +
// relu/pairmax/mean + R4 head (verbatim).
// R20 pool deltas vs R4 (structure otherwise untouched):
//  - per-o constants (row offsets iy0/iy1, wy, gate) precomputed to LDS
//  - 8 gathers/iter (2 y-rows x 2 x-taps x 2 k-halves), all independent
//  - 8 MFMAs/dt; x-lerp then y-lerp then gate (g>0: relu/max commute) —
//    exact by linearity; pairmax/accumulation unchanged
// Head: VERBATIM R4 — 7 structural variants all regressed; do not edit.
// ---------------------------------------------------------------------------
template<int W, int H>
__global__ __launch_bounds__(256) void fused_pool_head_kernel(
    const unsigned short* __restrict__ tab,   // [B][H][W+1][64] bf16 raw
    const float* __restrict__ xsrc, const int xstride,
    const float* __restrict__ lw,             // l_weight [72]
    const float* __restrict__ lsgi,           // [64][64] this stage
    float* __restrict__ sumFeat,              // [B*NP][64]
    const int stage,
    const float* __restrict__ fc_w,  const float* __restrict__ fc_b,
    const float* __restrict__ cls_w, const float* __restrict__ cls_b,
    const float* __restrict__ cls_ow, const float* __restrict__ cls_ob,
    const float* __restrict__ reg_w, const float* __restrict__ reg_b,
    const float* __restrict__ reg_ow, const float* __restrict__ reg_ob,
    const float* __restrict__ loc_w, const float* __restrict__ loc_b,
    const float* __restrict__ loc_ow, const float* __restrict__ loc_ob,
    float* __restrict__ out, float* __restrict__ xs_next)
{
    constexpr int Wp = W + 1;
    __shared__ __align__(16) float sF  [8][68];
    __shared__ __align__(16) float bufC[8][64];
    __shared__ __align__(16) float bufA[8][64];
    __shared__ __align__(16) float bufB[8][64];
    __shared__ int   sOff0[72];
    __shared__ int   sOff1[72];
    __shared__ float sWyA [72];
    __shared__ float sGate[72];

    const int tid  = threadIdx.x;
    const int w    = tid >> 6;
    const int lane = tid & 63;
    const int ng   = blockIdx.x >> 5;         // 0..23
    const int b    = blockIdx.x & 31;
    const int npair = ng * 4 + w;             // 0..95

    // per-o constants -> LDS
    if (tid < 72) {
        const float ys = 1.0f - (float)tid * (1.0f / 71.0f);
        const float iy = ys * (float)(H - 1);
        const float fy = floorf(iy);
        int iy0 = (int)fy; iy0 = iy0 < 0 ? 0 : (iy0 > H - 1 ? H - 1 : iy0);
        const int iy1 = (iy0 + 1 > H - 1) ? H - 1 : iy0 + 1;
        sOff0[tid] = iy0 * (Wp * 64);
        sOff1[tid] = iy1 * (Wp * 64);
        sWyA [tid] = iy - fy;
        sGate[tid] = 1.0f / (1.0f + __expf(-lw[tid]));
    }

    // ---------------- pool ----------------
    short8 wf[4][2];
    {
        const int kb = ((lane >> 4) & 3) * 8;
        const int dl = lane & 15;
        #pragma unroll
        for (int ks = 0; ks < 2; ++ks)
            #pragma unroll
            for (int dt = 0; dt < 4; ++dt) {
                union { unsigned short u[8]; short8 v; } pk;
                #pragma unroll
                for (int j = 0; j < 8; ++j)
                    pk.u[j] = f2bf(lsgi[(ks * 32 + kb + j) * 64 + dt * 16 + dl]);
                wf[dt][ks] = pk.v;
            }
    }
    __syncthreads();   // sOff/sWy/sGate ready

    const unsigned short* tb = tab + (size_t)b * H * Wp * 64;
    const float* xp = xsrc + (size_t)xstride * b;
    const int m  = lane & 15;
    const int kg = lane >> 4;
    const int nt0 = npair * 9;

    float sums0[4] = {0.f, 0.f, 0.f, 0.f};
    float sums1[4] = {0.f, 0.f, 0.f, 0.f};

    #pragma unroll
    for (int ntl = 0; ntl < 9; ++ntl) {
        const int pt = (nt0 + ntl) * 16 + m;
        const int o  = pt % NOq;
        float ixf = xp[pt] * (float)(W - 1);
        ixf = fminf(fmaxf(ixf, 0.0f), (float)(W - 1));
        const float fx = floorf(ixf);
        const float wx = ixf - fx;
        const int ix0 = (int)fx;

        const int xoff = ix0 * 64 + kg * 8;
        const unsigned short* c0p = tb + sOff0[o] + xoff;
        const unsigned short* c1p = tb + sOff1[o] + xoff;
        const short8 a00 = *(const short8*)(c0p);        // y0 tap0 k-lo
        const short8 a01 = *(const short8*)(c0p + 64);   // y0 tap1 k-lo
        const short8 a10 = *(const short8*)(c0p + 32);   // y0 tap0 k-hi
        const short8 a11 = *(const short8*)(c0p + 96);   // y0 tap1 k-hi
        const short8 b00 = *(const short8*)(c1p);        // y1 tap0 k-lo
        const short8 b01 = *(const short8*)(c1p + 64);   // y1 tap1 k-lo
        const short8 b10 = *(const short8*)(c1p + 32);   // y1 tap0 k-hi
        const short8 b11 = *(const short8*)(c1p + 96);   // y1 tap1 k-hi

        const float wy_l = sWyA[o];
        const float g_l  = sGate[o];

        // per-C-row constants (rows kg*4 .. kg*4+3 of this tile)
        float wxr[4], wyr[4], gr[4];
        #pragma unroll
        for (int j = 0; j < 4; ++j) {
            wxr[j] = __shfl(wx,   kg * 4 + j);
            wyr[j] = __shfl(wy_l, kg * 4 + j);
            gr [j] = __shfl(g_l,  kg * 4 + j);
        }

        const bool hi = (ntl * 16 + (kg * 4)) >= NOq;
        #pragma unroll
        for (int dt = 0; dt < 4; ++dt) {
            float4v cx0y0 = {0.f, 0.f, 0.f, 0.f};
            float4v cx1y0 = {0.f, 0.f, 0.f, 0.f};
            float4v cx0y1 = {0.f, 0.f, 0.f, 0.f};
            float4v cx1y1 = {0.f, 0.f, 0.f, 0.f};
            cx0y0 = __builtin_amdgcn_mfma_f32_16x16x32_bf16(a00, wf[dt][0], cx0y0, 0, 0, 0);
            cx0y0 = __builtin_amdgcn_mfma_f32_16x16x32_bf16(a10, wf[dt][1], cx0y0, 0, 0, 0);
            cx1y0 = __builtin_amdgcn_mfma_f32_16x16x32_bf16(a01, wf[dt][0], cx1y0, 0, 0, 0);
            cx1y0 = __builtin_amdgcn_mfma_f32_16x16x32_bf16(a11, wf[dt][1], cx1y0, 0, 0, 0);
            cx0y1 = __builtin_amdgcn_mfma_f32_16x16x32_bf16(b00, wf[dt][0], cx0y1, 0, 0, 0);
            cx0y1 = __builtin_amdgcn_mfma_f32_16x16x32_bf16(b10, wf[dt][1], cx0y1, 0, 0, 0);
            cx1y1 = __builtin_amdgcn_mfma_f32_16x16x32_bf16(b01, wf[dt][0], cx1y1, 0, 0, 0);
            cx1y1 = __builtin_amdgcn_mfma_f32_16x16x32_bf16(b11, wf[dt][1], cx1y1, 0, 0, 0);
            float v[4];
            #pragma unroll
            for (int j = 0; j < 4; ++j) {
                const float vy0 = cx0y0[j] + wxr[j] * (cx1y0[j] - cx0y0[j]);
                const float vy1 = cx0y1[j] + wxr[j] * (cx1y1[j] - cx0y1[j]);
                v[j] = (vy0 + wyr[j] * (vy1 - vy0)) * gr[j];
            }
            const float pm0 = fmaxf(fmaxf(v[0], v[1]), 0.f);
            const float pm1 = fmaxf(fmaxf(v[2], v[3]), 0.f);
            const float add = pm0 + pm1;
            if (hi) sums1[dt] += add; else sums0[dt] += add;
        }
    }

    #pragma unroll
    for (int dt = 0; dt < 4; ++dt) {
        float v0 = sums0[dt], v1 = sums1[dt];
        v0 += __shfl_xor(v0, 16); v0 += __shfl_xor(v0, 32);
        v1 += __shfl_xor(v1, 16); v1 += __shfl_xor(v1, 32);
        sums0[dt] = v0; sums1[dt] = v1;
    }

    const float invS = 1.0f / (float)(stage + 1);
    if (lane < 16) {
        const size_t row0 = (size_t)(b * NPq + npair * 2) * 64;
        #pragma unroll
        for (int dt = 0; dt < 4; ++dt) {
            const int d = dt * 16 + lane;
            float t0 = sums0[dt] * (1.0f / 36.0f);
            float t1 = sums1[dt] * (1.0f / 36.0f);
            float* p0 = sumFeat + row0 + d;
            float* p1 = sumFeat + row0 + 64 + d;
            if (stage > 0) { t0 += *p0; t1 += *p1; }
            *p0 = t0; *p1 = t1;
            sF[2 * w][d]     = t0 * invS;
            sF[2 * w + 1][d] = t1 * invS;
        }
    }
    __syncthreads();   // sF published cross-wave

    // ---------------- head: wave-per-point-pair, barrier-free (R4) --------
    const int pA  = w;
    const int pB  = w + 4;
    const int p0g = b * NPq + ng * 8;  // global point base

    auto layer = [&](const float* iA, const float* iB, float* oA, float* oB,
                     const float* __restrict__ gw, const float* __restrict__ gb) {
        const float bias = gb[lane];
        float accA = bias, accB = bias;
        #pragma unroll 4
        for (int k = 0; k < 64; k += 4) {
            const float4 a4 = *(const float4*)(iA + k);   // LDS broadcast
            const float4 b4 = *(const float4*)(iB + k);
            const float w0 = gw[(k + 0) * 64 + lane];     // coalesced 256B row
            const float w1 = gw[(k + 1) * 64 + lane];
            const float w2 = gw[(k + 2) * 64 + lane];
            const float w3 = gw[(k + 3) * 64 + lane];
            accA += a4.x * w0 + a4.y * w1 + a4.z * w2 + a4.w * w3;
            accB += b4.x * w0 + b4.y * w1 + b4.z * w2 + b4.w * w3;
        }
        oA[lane] = fmaxf(accA, 0.f);
        oB[lane] = fmaxf(accB, 0.f);
        __builtin_amdgcn_wave_barrier();   // same-wave DS is in-order
    };

    // fc
    layer(sF[pA], sF[pB], bufC[pA], bufC[pB], fc_w, fc_b);

    // ---- cls ----
    layer(bufC[pA], bufC[pB], bufA[pA], bufA[pB], cls_w,        cls_b);
    layer(bufA[pA], bufA[pB], bufB[pA], bufB[pB], cls_w + 4096, cls_b + 64);
    {
        const float bA = bufB[pA][lane], bB = bufB[pB][lane];
        const float2 ow = *(const float2*)&cls_ow[lane * 2];
        float v0 = bA * ow.x, v1 = bA * ow.y;
        float v2 = bB * ow.x, v3 = bB * ow.y;
        #pragma unroll
        for (int m2 = 1; m2 < 64; m2 <<= 1) {
            v0 += __shfl_xor(v0, m2);
            v1 += __shfl_xor(v1, m2);
            v2 += __shfl_xor(v2, m2);
            v3 += __shfl_xor(v3, m2);
        }
        if (lane == 0) {
            out[(size_t)(p0g + pA) * OUTD + 0] = v0 + cls_ob[0];
            out[(size_t)(p0g + pA) * OUTD + 1] = v1 + cls_ob[1];
            out[(size_t)(p0g + pB) * OUTD + 0] = v2 + cls_ob[0];
            out[(size_t)(p0g + pB) * OUTD + 1] = v3 + cls_ob[1];
        }
    }

    // ---- reg ----
    layer(bufC[pA], bufC[pB], bufA[pA], bufA[pB], reg_w,        reg_b);
    layer(bufA[pA], bufA[pB], bufB[pA], bufB[pB], reg_w + 4096, reg_b + 64);
    {
        const int j1 = lane;                              // 0..63
        const int j2 = (lane < 12) ? 64 + lane : 75;      // clamped (in-bounds loads)
        float zA1 = reg_ob[j1], zB1 = zA1;
        float zA2 = reg_ob[j2], zB2 = zA2;
        #pragma unroll 4
        for (int k = 0; k < 64; k += 4) {
            const float4 a4 = *(const float4*)&bufB[pA][k];
            const float4 b4 = *(const float4*)&bufB[pB][k];
            const float u0 = reg_ow[(k + 0) * REGD + j1];
            const float u1 = reg_ow[(k + 1) * REGD + j1];
            const float u2 = reg_ow[(k + 2) * REGD + j1];
            const float u3 = reg_ow[(k + 3) * REGD + j1];
            const float t0 = reg_ow[(k + 0) * REGD + j2];
            const float t1 = reg_ow[(k + 1) * REGD + j2];
            const float t2 = reg_ow[(k + 2) * REGD + j2];
            const float t3 = reg_ow[(k + 3) * REGD + j2];
            zA1 += a4.x * u0 + a4.y * u1 + a4.z * u2 + a4.w * u3;
            zB1 += b4.x * u0 + b4.y * u1 + b4.z * u2 + b4.w * u3;
            zA2 += a4.x * t0 + a4.y * t1 + a4.z * t2 + a4.w * t3;
            zB2 += b4.x * t0 + b4.y * t1 + b4.z * t2 + b4.w * t3;
        }
        float* orA = out + (size_t)(p0g + pA) * OUTD;
        float* orB = out + (size_t)(p0g + pB) * OUTD;
        float* xsA = xs_next + (size_t)(p0g + pA) * NOq;
        float* xsB = xs_next + (size_t)(p0g + pB) * NOq;
        orA[2 + j1] = zA1;
        orB[2 + j1] = zB1;
        if (lane >= 4) {
            xsA[j1 - 4] = 1.0f / (1.0f + __expf(-zA1));
            xsB[j1 - 4] = 1.0f / (1.0f + __expf(-zB1));
        }
        if (lane < 12) {
            orA[2 + j2] = zA2;
            orB[2 + j2] = zB2;
            xsA[j2 - 4] = 1.0f / (1.0f + __expf(-zA2));
            xsB[j2 - 4] = 1.0f / (1.0f + __expf(-zB2));
        }
    }

    // ---- loc ----
    layer(bufC[pA], bufC[pB], bufA[pA], bufA[pB], loc_w,        loc_b);
    layer(bufA[pA], bufA[pB], bufB[pA], bufB[pB], loc_w + 4096, loc_b + 64);
    {
        float v0 = bufB[pA][lane] * loc_ow[lane];
        float v1 = bufB[pB][lane] * loc_ow[lane];
        #pragma unroll
        for (int m2 = 1; m2 < 64; m2 <<= 1) {
            v0 += __shfl_xor(v0, m2);
            v1 += __shfl_xor(v1, m2);
        }
        if (lane == 0) {
            out[(size_t)(p0g + pA) * OUTD + 78] = v0 + loc_ob[0];
            out[(size_t)(p0g + pB) * OUTD + 78] = v1 + loc_ob[0];
        }
    }
}

// ---------------------------------------------------------------------------
extern "C" void kernel_launch(void* const* d_in, const int* in_sizes, int n_in,
                              void* d_out, int out_size, void* d_ws, size_t ws_size,
                              hipStream_t stream)
{
    const float* x0        = (const float*)d_in[0];
    const float* x1        = (const float*)d_in[1];
    const float* x2        = (const float*)d_in[2];
    const float* prior_xs0 = (const float*)d_in[3];
    const float* l_weight  = (const float*)d_in[4];
    const float* lsgi_w    = (const float*)d_in[5];
    const float* fc_w      = (const float*)d_in[6];
    const float* fc_b      = (const float*)d_in[7];
    const float* cls_w     = (const float*)d_in[8];
    const float* cls_b     = (const float*)d_in[9];
    const float* cls_ow    = (const float*)d_in[10];
    const float* cls_ob    = (const float*)d_in[11];
    const float* reg_w     = (const float*)d_in[12];
    const float* reg_b     = (const float*)d_in[13];
    const float* reg_ow    = (const float*)d_in[14];
    const float* reg_ob    = (const float*)d_in[15];
    const float* loc_w     = (const float*)d_in[16];
    const float* loc_b     = (const float*)d_in[17];
    const float* loc_ow    = (const float*)d_in[18];
    const float* loc_ob    = (const float*)d_in[19];

    float* out     = (float*)d_out;
    float* sumFeat = (float*)d_ws;                               // [6144][64] f32
    float* xs      = sumFeat + (size_t)Bq * NPq * Cq;            // [6144][72] f32
    unsigned short* tab0 = (unsigned short*)(xs + (size_t)Bq * PTS);
    unsigned short* tab1 = tab0 + (size_t)Bq * 10 * 26  * 64;    // H=10,Wp=26
    unsigned short* tab2 = tab1 + (size_t)Bq * 20 * 51  * 64;    // H=20,Wp=51

    hipLaunchKernelGGL(build_raw_kernel, dim3(2240), dim3(256), 0, stream,
                       x2, x1, x0, tab0, tab1, tab2);

    for (int s = 0; s < 3; ++s) {
        const float* xsrc = (s == 0) ? prior_xs0 : xs;
        const int xstr    = (s == 0) ? 0 : PTS;
        const unsigned short* tb = (s == 0) ? tab0 : (s == 1) ? tab1 : tab2;
        float* outS = out + (size_t)s * Bq * NPq * OUTD;
        if (s == 0)
            hipLaunchKernelGGL((fused_pool_head_kernel<25, 10>), dim3(Bq * 24), dim3(256), 0, stream,
                               tb, xsrc, xstr, l_weight, lsgi_w + s * 4096, sumFeat, s,
                               fc_w, fc_b, cls_w, cls_b, cls_ow, cls_ob,
                               reg_w, reg_b, reg_ow, reg_ob,
                               loc_w, loc_b, loc_ow, loc_ob, outS, xs);
        else if (s == 1)
            hipLaunchKernelGGL((fused_pool_head_kernel<50, 20>), dim3(Bq * 24), dim3(256), 0, stream,
                               tb, xsrc, xstr, l_weight, lsgi_w + s * 4096, sumFeat, s,
                               fc_w, fc_b, cls_w, cls_b, cls_ow, cls_ob,
                               reg_w, reg_b, reg_ow, reg_ob,
                               loc_w, loc_b, loc_ow, loc_ob, outS, xs);
        else
            hipLaunchKernelGGL((fused_pool_head_kernel<100, 40>), dim3(Bq * 24), dim3(256), 0, stream,
                               tb, xsrc, xstr, l_weight, lsgi_w + s * 4096, sumFeat, s,
                               fc_w, fc_b, cls_w, cls_b, cls_ow, cls_ob,
                               reg_w, reg_b, reg_ow, reg_ob,
                               loc_w, loc_b, loc_ow, loc_ob, outS, xs);
    }
}

// Round 12
// 246.184 us; speedup vs baseline: 1.2476x; 1.2476x over previous
//
#include <hip/hip_runtime.h>
#include <hip/hip_bf16.h>

#define Bq   32
#define Cq   64
#define NPq  192
#define NOq  72
#define PTS  (NPq * NOq)   // 13824
#define REGD 76
#define OUTD 79

typedef __attribute__((ext_vector_type(8))) short short8;
typedef __attribute__((ext_vector_type(4))) float float4v;

__device__ inline unsigned short f2bf(float x) {
    __hip_bfloat16 h = __float2bfloat16(x);
    return *reinterpret_cast<unsigned short*>(&h);
}

// ---------------------------------------------------------------------------
// Phase 0 (once): build gated y-blended tables for ALL 3 stages.
// EXACT R8 form — global-best configuration (R4, 242.6us total).
// tab[s][b][o][x][c] bf16, x in [0..W] (x=W replicates W-1), c innermost.
// ---------------------------------------------------------------------------
__global__ __launch_bounds__(256) void build_tables_kernel(
    const float* __restrict__ f0,   // x2: H=10,W=25
    const float* __restrict__ f1,   // x1: H=20,W=50
    const float* __restrict__ f2,   // x0: H=40,W=100
    const float* __restrict__ lw,
    unsigned short* __restrict__ t0,
    unsigned short* __restrict__ t1,
    unsigned short* __restrict__ t2)
{
    __shared__ float sRow[64 * 101];

    const int tid = threadIdx.x;
    const int o   = blockIdx.x / 96;
    const int sb  = blockIdx.x - o * 96;
    const int s   = sb >> 5;
    const int b   = sb & 31;

    const float* feat; unsigned short* tab; int H, W;
    if (s == 0)      { feat = f0; tab = t0; H = 10; W = 25; }
    else if (s == 1) { feat = f1; tab = t1; H = 20; W = 50; }
    else             { feat = f2; tab = t2; H = 40; W = 100; }
    const int Wp = W + 1;

    const float ys = 1.0f - (float)o * (1.0f / 71.0f);
    const float iy = ys * (float)(H - 1);
    const float fy = floorf(iy);
    const float wy = iy - fy;
    int iy0 = (int)fy; iy0 = iy0 < 0 ? 0 : (iy0 > H - 1 ? H - 1 : iy0);
    const int iy1 = (iy0 + 1 > H - 1) ? H - 1 : iy0 + 1;
    const float gate = 1.0f / (1.0f + __expf(-lw[o]));

    const float* fb = feat + (size_t)b * 64 * H * W;
    const int iy0W = iy0 * W, iy1W = iy1 * W;

    // blend rows -> LDS [c][x] fp32
    const int tot = 64 * W;
    for (int idx = tid; idx < tot; idx += 256) {
        const int c = idx / W;
        const int x = idx - c * W;
        const float* f = fb + c * (H * W);
        sRow[c * Wp + x] = ((1.0f - wy) * f[iy0W + x] + wy * f[iy1W + x]) * gate;
    }
    __syncthreads();

    // write transposed [x][c] bf16 (c-major coalesced), pad x=W
    unsigned short* to = tab + (size_t)(b * NOq + o) * Wp * 64;
    const int tot2 = Wp * 64;
    for (int idx = tid; idx < tot2; idx += 256) {
        const int x = idx >> 6;
        const int c = idx & 63;
        const int xx = (x < W) ? x : (W - 1);
        to[idx] = f2bf(sRow[c * Wp + xx]);
    }
}

// ---------------------------------------------------------------------------
// Fused: table gather + MFMA pool (R0/R8 form) + wave-per-point head.
// EXACT R4 form — global-best measured (242.6us total). Eight structural
// variants (R11/R12/R12b/R15/R16/R17/R18/R20) all regressed. The pool is
// gather-issue-bound: time scales ~linearly with gathers/iter (R6, R20);
// current gather count is the algorithmic minimum for this access pattern.
// ---------------------------------------------------------------------------
template<int W>
__global__ __launch_bounds__(256) void fused_pool_head_kernel(
    const unsigned short* __restrict__ tab,   // [B][72][W+1][64] bf16
    const float* __restrict__ xsrc, const int xstride,
    const float* __restrict__ lsgi,           // [64][64] this stage
    float* __restrict__ sumFeat,              // [B*NP][64]
    const int stage,
    const float* __restrict__ fc_w,  const float* __restrict__ fc_b,
    const float* __restrict__ cls_w, const float* __restrict__ cls_b,
    const float* __restrict__ cls_ow, const float* __restrict__ cls_ob,
    const float* __restrict__ reg_w, const float* __restrict__ reg_b,
    const float* __restrict__ reg_ow, const float* __restrict__ reg_ob,
    const float* __restrict__ loc_w, const float* __restrict__ loc_b,
    const float* __restrict__ loc_ow, const float* __restrict__ loc_ob,
    float* __restrict__ out, float* __restrict__ xs_next)
{
    constexpr int Wp = W + 1;
    __shared__ __align__(16) float sF  [8][68];
    __shared__ __align__(16) float bufC[8][64];
    __shared__ __align__(16) float bufA[8][64];
    __shared__ __align__(16) float bufB[8][64];

    const int tid  = threadIdx.x;
    const int w    = tid >> 6;
    const int lane = tid & 63;
    const int ng   = blockIdx.x >> 5;         // 0..23
    const int b    = blockIdx.x & 31;
    const int npair = ng * 4 + w;             // 0..95

    // ---------------- pool (verbatim R0) ----------------
    short8 wf[4][2];
    {
        const int kb = ((lane >> 4) & 3) * 8;
        const int dl = lane & 15;
        #pragma unroll
        for (int ks = 0; ks < 2; ++ks)
            #pragma unroll
            for (int dt = 0; dt < 4; ++dt) {
                union { unsigned short u[8]; short8 v; } pk;
                #pragma unroll
                for (int j = 0; j < 8; ++j)
                    pk.u[j] = f2bf(lsgi[(ks * 32 + kb + j) * 64 + dt * 16 + dl]);
                wf[dt][ks] = pk.v;
            }
    }

    const unsigned short* tb = tab + (size_t)b * NOq * Wp * 64;
    const float* xp = xsrc + (size_t)xstride * b;
    const int m  = lane & 15;
    const int kg = lane >> 4;
    const int nt0 = npair * 9;

    float sums0[4] = {0.f, 0.f, 0.f, 0.f};
    float sums1[4] = {0.f, 0.f, 0.f, 0.f};

    #pragma unroll
    for (int ntl = 0; ntl < 9; ++ntl) {
        const int pt = (nt0 + ntl) * 16 + m;
        const int o  = pt % NOq;
        float ixf = xp[pt] * (float)(W - 1);
        ixf = fminf(fmaxf(ixf, 0.0f), (float)(W - 1));
        const float fx = floorf(ixf);
        const float wx = ixf - fx;
        const int ix0 = (int)fx;

        const unsigned short* col = tb + ((size_t)o * Wp + ix0) * 64 + kg * 8;
        const short8 a00 = *(const short8*)(col);        // tap0, k-lo
        const short8 a01 = *(const short8*)(col + 64);   // tap1, k-lo
        const short8 a10 = *(const short8*)(col + 32);   // tap0, k-hi
        const short8 a11 = *(const short8*)(col + 96);   // tap1, k-hi

        // per-C-row wx (rows kg*4 .. kg*4+3 of this tile)
        float wxr[4];
        #pragma unroll
        for (int j = 0; j < 4; ++j) wxr[j] = __shfl(wx, kg * 4 + j);

        const bool hi = (ntl * 16 + (kg * 4)) >= NOq;
        #pragma unroll
        for (int dt = 0; dt < 4; ++dt) {
            float4v c0 = {0.f, 0.f, 0.f, 0.f};
            float4v c1 = {0.f, 0.f, 0.f, 0.f};
            c0 = __builtin_amdgcn_mfma_f32_16x16x32_bf16(a00, wf[dt][0], c0, 0, 0, 0);
            c0 = __builtin_amdgcn_mfma_f32_16x16x32_bf16(a10, wf[dt][1], c0, 0, 0, 0);
            c1 = __builtin_amdgcn_mfma_f32_16x16x32_bf16(a01, wf[dt][0], c1, 0, 0, 0);
            c1 = __builtin_amdgcn_mfma_f32_16x16x32_bf16(a11, wf[dt][1], c1, 0, 0, 0);
            const float v0 = c0[0] + wxr[0] * (c1[0] - c0[0]);
            const float v1 = c0[1] + wxr[1] * (c1[1] - c0[1]);
            const float v2 = c0[2] + wxr[2] * (c1[2] - c0[2]);
            const float v3 = c0[3] + wxr[3] * (c1[3] - c0[3]);
            const float pm0 = fmaxf(fmaxf(v0, v1), 0.f);
            const float pm1 = fmaxf(fmaxf(v2, v3), 0.f);
            const float add = pm0 + pm1;
            if (hi) sums1[dt] += add; else sums0[dt] += add;
        }
    }

    #pragma unroll
    for (int dt = 0; dt < 4; ++dt) {
        float v0 = sums0[dt], v1 = sums1[dt];
        v0 += __shfl_xor(v0, 16); v0 += __shfl_xor(v0, 32);
        v1 += __shfl_xor(v1, 16); v1 += __shfl_xor(v1, 32);
        sums0[dt] = v0; sums1[dt] = v1;
    }

    const float invS = 1.0f / (float)(stage + 1);
    if (lane < 16) {
        const size_t row0 = (size_t)(b * NPq + npair * 2) * 64;
        #pragma unroll
        for (int dt = 0; dt < 4; ++dt) {
            const int d = dt * 16 + lane;
            float t0 = sums0[dt] * (1.0f / 36.0f);
            float t1 = sums1[dt] * (1.0f / 36.0f);
            float* p0 = sumFeat + row0 + d;
            float* p1 = sumFeat + row0 + 64 + d;
            if (stage > 0) { t0 += *p0; t1 += *p1; }
            *p0 = t0; *p1 = t1;
            sF[2 * w][d]     = t0 * invS;
            sF[2 * w + 1][d] = t1 * invS;
        }
    }
    __syncthreads();   // sF published cross-wave; ONLY barrier in the head

    // ---------------- head: wave-per-point, barrier-free ----------------
    const int pA  = w;
    const int pB  = w + 4;
    const int p0g = b * NPq + ng * 8;  // global point base

    auto layer = [&](const float* iA, const float* iB, float* oA, float* oB,
                     const float* __restrict__ gw, const float* __restrict__ gb) {
        const float bias = gb[lane];
        float accA = bias, accB = bias;
        #pragma unroll 4
        for (int k = 0; k < 64; k += 4) {
            const float4 a4 = *(const float4*)(iA + k);   // LDS broadcast
            const float4 b4 = *(const float4*)(iB + k);
            const float w0 = gw[(k + 0) * 64 + lane];     // coalesced 256B row
            const float w1 = gw[(k + 1) * 64 + lane];
            const float w2 = gw[(k + 2) * 64 + lane];
            const float w3 = gw[(k + 3) * 64 + lane];
            accA += a4.x * w0 + a4.y * w1 + a4.z * w2 + a4.w * w3;
            accB += b4.x * w0 + b4.y * w1 + b4.z * w2 + b4.w * w3;
        }
        oA[lane] = fmaxf(accA, 0.f);
        oB[lane] = fmaxf(accB, 0.f);
        __builtin_amdgcn_wave_barrier();   // compile-time fence (same-wave DS is in-order)
    };

    // fc
    layer(sF[pA], sF[pB], bufC[pA], bufC[pB], fc_w, fc_b);

    // ---- cls ----
    layer(bufC[pA], bufC[pB], bufA[pA], bufA[pB], cls_w,        cls_b);
    layer(bufA[pA], bufA[pB], bufB[pA], bufB[pB], cls_w + 4096, cls_b + 64);
    {
        const float bA = bufB[pA][lane], bB = bufB[pB][lane];
        const float2 ow = *(const float2*)&cls_ow[lane * 2];
        float v0 = bA * ow.x, v1 = bA * ow.y;
        float v2 = bB * ow.x, v3 = bB * ow.y;
        #pragma unroll
        for (int m2 = 1; m2 < 64; m2 <<= 1) {
            v0 += __shfl_xor(v0, m2);
            v1 += __shfl_xor(v1, m2);
            v2 += __shfl_xor(v2, m2);
            v3 += __shfl_xor(v3, m2);
        }
        if (lane == 0) {
            out[(size_t)(p0g + pA) * OUTD + 0] = v0 + cls_ob[0];
            out[(size_t)(p0g + pA) * OUTD + 1] = v1 + cls_ob[1];
            out[(size_t)(p0g + pB) * OUTD + 0] = v2 + cls_ob[0];
            out[(size_t)(p0g + pB) * OUTD + 1] = v3 + cls_ob[1];
        }
    }

    // ---- reg ----
    layer(bufC[pA], bufC[pB], bufA[pA], bufA[pB], reg_w,        reg_b);
    layer(bufA[pA], bufA[pB], bufB[pA], bufB[pB], reg_w + 4096, reg_b + 64);
    {
        const int j1 = lane;                              // 0..63
        const int j2 = (lane < 12) ? 64 + lane : 75;      // clamped (in-bounds loads)
        float zA1 = reg_ob[j1], zB1 = zA1;
        float zA2 = reg_ob[j2], zB2 = zA2;
        #pragma unroll 4
        for (int k = 0; k < 64; k += 4) {
            const float4 a4 = *(const float4*)&bufB[pA][k];
            const float4 b4 = *(const float4*)&bufB[pB][k];
            const float u0 = reg_ow[(k + 0) * REGD + j1];
            const float u1 = reg_ow[(k + 1) * REGD + j1];
            const float u2 = reg_ow[(k + 2) * REGD + j1];
            const float u3 = reg_ow[(k + 3) * REGD + j1];
            const float t0 = reg_ow[(k + 0) * REGD + j2];
            const float t1 = reg_ow[(k + 1) * REGD + j2];
            const float t2 = reg_ow[(k + 2) * REGD + j2];
            const float t3 = reg_ow[(k + 3) * REGD + j2];
            zA1 += a4.x * u0 + a4.y * u1 + a4.z * u2 + a4.w * u3;
            zB1 += b4.x * u0 + b4.y * u1 + b4.z * u2 + b4.w * u3;
            zA2 += a4.x * t0 + a4.y * t1 + a4.z * t2 + a4.w * t3;
            zB2 += b4.x * t0 + b4.y * t1 + b4.z * t2 + b4.w * t3;
        }
        float* orA = out + (size_t)(p0g + pA) * OUTD;
        float* orB = out + (size_t)(p0g + pB) * OUTD;
        float* xsA = xs_next + (size_t)(p0g + pA) * NOq;
        float* xsB = xs_next + (size_t)(p0g + pB) * NOq;
        orA[2 + j1] = zA1;
        orB[2 + j1] = zB1;
        if (lane >= 4) {
            xsA[j1 - 4] = 1.0f / (1.0f + __expf(-zA1));
            xsB[j1 - 4] = 1.0f / (1.0f + __expf(-zB1));
        }
        if (lane < 12) {
            orA[2 + j2] = zA2;
            orB[2 + j2] = zB2;
            xsA[j2 - 4] = 1.0f / (1.0f + __expf(-zA2));
            xsB[j2 - 4] = 1.0f / (1.0f + __expf(-zB2));
        }
    }

    // ---- loc ----
    layer(bufC[pA], bufC[pB], bufA[pA], bufA[pB], loc_w,        loc_b);
    layer(bufA[pA], bufA[pB], bufB[pA], bufB[pB], loc_w + 4096, loc_b + 64);
    {
        float v0 = bufB[pA][lane] * loc_ow[lane];
        float v1 = bufB[pB][lane] * loc_ow[lane];
        #pragma unroll
        for (int m2 = 1; m2 < 64; m2 <<= 1) {
            v0 += __shfl_xor(v0, m2);
            v1 += __shfl_xor(v1, m2);
        }
        if (lane == 0) {
            out[(size_t)(p0g + pA) * OUTD + 78] = v0 + loc_ob[0];
            out[(size_t)(p0g + pB) * OUTD + 78] = v1 + loc_ob[0];
        }
    }
}

// ---------------------------------------------------------------------------
extern "C" void kernel_launch(void* const* d_in, const int* in_sizes, int n_in,
                              void* d_out, int out_size, void* d_ws, size_t ws_size,
                              hipStream_t stream)
{
    const float* x0        = (const float*)d_in[0];
    const float* x1        = (const float*)d_in[1];
    const float* x2        = (const float*)d_in[2];
    const float* prior_xs0 = (const float*)d_in[3];
    const float* l_weight  = (const float*)d_in[4];
    const float* lsgi_w    = (const float*)d_in[5];
    const float* fc_w      = (const float*)d_in[6];
    const float* fc_b      = (const float*)d_in[7];
    const float* cls_w     = (const float*)d_in[8];
    const float* cls_b     = (const float*)d_in[9];
    const float* cls_ow    = (const float*)d_in[10];
    const float* cls_ob    = (const float*)d_in[11];
    const float* reg_w     = (const float*)d_in[12];
    const float* reg_b     = (const float*)d_in[13];
    const float* reg_ow    = (const float*)d_in[14];
    const float* reg_ob    = (const float*)d_in[15];
    const float* loc_w     = (const float*)d_in[16];
    const float* loc_b     = (const float*)d_in[17];
    const float* loc_ow    = (const float*)d_in[18];
    const float* loc_ob    = (const float*)d_in[19];

    float* out     = (float*)d_out;
    float* sumFeat = (float*)d_ws;                               // [6144][64] f32
    float* xs      = sumFeat + (size_t)Bq * NPq * Cq;            // [6144][72] f32
    unsigned short* tab0 = (unsigned short*)(xs + (size_t)Bq * PTS);
    unsigned short* tab1 = tab0 + (size_t)Bq * NOq * 26  * 64;   // W=25
    unsigned short* tab2 = tab1 + (size_t)Bq * NOq * 51  * 64;   // W=50

    hipLaunchKernelGGL(build_tables_kernel, dim3(3 * Bq * NOq), dim3(256), 0, stream,
                       x2, x1, x0, l_weight, tab0, tab1, tab2);

    for (int s = 0; s < 3; ++s) {
        const float* xsrc = (s == 0) ? prior_xs0 : xs;
        const int xstr    = (s == 0) ? 0 : PTS;
        const unsigned short* tb = (s == 0) ? tab0 : (s == 1) ? tab1 : tab2;
        float* outS = out + (size_t)s * Bq * NPq * OUTD;
        if (s == 0)
            hipLaunchKernelGGL((fused_pool_head_kernel<25>), dim3(Bq * 24), dim3(256), 0, stream,
                               tb, xsrc, xstr, lsgi_w + s * 4096, sumFeat, s,
                               fc_w, fc_b, cls_w, cls_b, cls_ow, cls_ob,
                               reg_w, reg_b, reg_ow, reg_ob,
                               loc_w, loc_b, loc_ow, loc_ob, outS, xs);
        else if (s == 1)
            hipLaunchKernelGGL((fused_pool_head_kernel<50>), dim3(Bq * 24), dim3(256), 0, stream,
                               tb, xsrc, xstr, lsgi_w + s * 4096, sumFeat, s,
                               fc_w, fc_b, cls_w, cls_b, cls_ow, cls_ob,
                               reg_w, reg_b, reg_ow, reg_ob,
                               loc_w, loc_b, loc_ow, loc_ob, outS, xs);
        else
            hipLaunchKernelGGL((fused_pool_head_kernel<100>), dim3(Bq * 24), dim3(256), 0, stream,
                               tb, xsrc, xstr, lsgi_w + s * 4096, sumFeat, s,
                               fc_w, fc_b, cls_w, cls_b, cls_ow, cls_ob,
                               reg_w, reg_b, reg_ow, reg_ob,
                               loc_w, loc_b, loc_ow, loc_ob, outS, xs);
    }
}